// Round 1
// baseline (419.703 us; speedup 1.0000x reference)
//
#include <hip/hip_runtime.h>

// Problem constants (fixed by reference setup_inputs)
#define BB   2048   // batch
#define LL   20     // seq length
#define JJ   25     // joints
#define CC   256    // channels
#define FF   64     // filters
#define KK   4      // hops
#define JPAD 28     // padded row length for aligned float4 reads of M rows

// out[l,b,i,c] = sum_j M[l,i,j] * x[b,l,j,c]
// M[l,i,j]     = sum_k w[k,l] * A[i,j]^k   (elementwise power, Horner)
// w[k,l]       = sum_n kernel[n,k,l]
//
// Grid: LL * (BB/4) blocks; block = 256 threads = 4 batch-subs x 64 float4 cols.
__global__ __launch_bounds__(256) void GCNLayer_72602127172024_kernel(
    const float* __restrict__ x,     // [B,L,J,C]
    const float* __restrict__ A,     // [J,J]
    const float* __restrict__ kern,  // [F,K,L]
    float* __restrict__ out)         // [L,B,J,C]
{
    __shared__ float w_sh[KK];
    __shared__ float Ms[JJ * JPAD];   // Ms[i*JPAD + j] = M[i][j], pad zeroed

    const int tid = threadIdx.x;
    const int gid = blockIdx.x;
    const int l   = gid >> 9;          // / (BB/4) == /512
    const int bb  = (gid & 511) << 2;  // base batch of this block (4 consecutive b)

    // ---- w[k] = sum_n kern[n*K*L + k*L + l]; wave k handles hop k, lane = n ----
    {
        const int k    = tid >> 6;   // wave id == hop (KK==4 waves exactly)
        const int lane = tid & 63;   // filter index (FF==64 exactly)
        float v = kern[lane * (KK * LL) + k * LL + l];
        v += __shfl_xor(v, 32, 64);
        v += __shfl_xor(v, 16, 64);
        v += __shfl_xor(v, 8, 64);
        v += __shfl_xor(v, 4, 64);
        v += __shfl_xor(v, 2, 64);
        v += __shfl_xor(v, 1, 64);
        if (lane == 0) w_sh[k] = v;
    }
    __syncthreads();

    const float w0 = w_sh[0], w1 = w_sh[1], w2 = w_sh[2], w3 = w_sh[3];

    // ---- build Ms[i][j] (row-major, padded); pad entries set to 0 ----
    for (int e = tid; e < JJ * JPAD; e += 256) {
        const int i = e / JPAD;
        const int j = e - i * JPAD;
        float m = 0.0f;
        if (j < JJ) {
            const float a = A[i * JJ + j];
            m = w0 + a * (w1 + a * (w2 + a * w3));   // Horner; a=0 -> w0 (0^0==1)
        }
        Ms[e] = m;
    }
    __syncthreads();

    // ---- main: each thread owns one float4 column of one (b,l) slab ----
    const int bsub = tid >> 6;       // 0..3
    const int c4   = tid & 63;       // float4 column
    const int b    = bb + bsub;

    const float4* __restrict__ xin =
        reinterpret_cast<const float4*>(x) + ((b * LL + l) * JJ) * 64 + c4;
    float4* __restrict__ oout =
        reinterpret_cast<float4*>(out) + ((l * BB + b) * JJ) * 64 + c4;

    // Load the full [J] column slab into registers (25 x float4 = 100 VGPR),
    // fully coalesced (wave reads 1KB per instruction).
    float4 xv[JJ];
#pragma unroll
    for (int j = 0; j < JJ; ++j) xv[j] = xin[j * 64];

    // For each output joint i: read M row i as 7 float4 LDS broadcasts,
    // accumulate, store immediately (keeps live registers bounded).
#pragma unroll
    for (int i = 0; i < JJ; ++i) {
        const float4* mrow = reinterpret_cast<const float4*>(Ms + i * JPAD);
        float4 acc;
        acc.x = 0.0f; acc.y = 0.0f; acc.z = 0.0f; acc.w = 0.0f;
#pragma unroll
        for (int j4 = 0; j4 < 7; ++j4) {
            const float4 m4 = mrow[j4];
#pragma unroll
            for (int comp = 0; comp < 4; ++comp) {
                const int j = j4 * 4 + comp;
                if (j < JJ) {   // compile-time pruned (full unroll)
                    const float m = (comp == 0) ? m4.x : (comp == 1) ? m4.y
                                   : (comp == 2) ? m4.z : m4.w;
                    acc.x = fmaf(m, xv[j].x, acc.x);
                    acc.y = fmaf(m, xv[j].y, acc.y);
                    acc.z = fmaf(m, xv[j].z, acc.z);
                    acc.w = fmaf(m, xv[j].w, acc.w);
                }
            }
        }
        oout[i * 64] = acc;
    }
}

extern "C" void kernel_launch(void* const* d_in, const int* in_sizes, int n_in,
                              void* d_out, int out_size, void* d_ws, size_t ws_size,
                              hipStream_t stream) {
    const float* x    = (const float*)d_in[0];   // [B,L,J,C]
    const float* A    = (const float*)d_in[1];   // [J,J]
    const float* kern = (const float*)d_in[2];   // [F,K,L]
    float* out        = (float*)d_out;           // [L,B,J,C]

    const int grid = LL * (BB / 4);  // 10240 blocks
    GCNLayer_72602127172024_kernel<<<grid, 256, 0, stream>>>(x, A, kern, out);
}

// Round 2
// 383.564 us; speedup vs baseline: 1.0942x; 1.0942x over previous
//
#include <hip/hip_runtime.h>

// Problem constants (fixed by reference setup_inputs)
#define BB   2048   // batch
#define LL   20     // seq length
#define JJ   25     // joints
#define CC   256    // channels
#define FF   64     // filters
#define KK   4      // hops
#define JPAD 28     // padded row length for aligned float4 reads of M rows

typedef float f2 __attribute__((ext_vector_type(2)));
typedef float f4 __attribute__((ext_vector_type(4)));

// out[l,b,i,c] = sum_j M[l,i,j] * x[b,l,j,c]
// M[l,i,j]     = sum_k w[k,l] * A[i,j]^k   (elementwise power, Horner)
// w[k,l]       = sum_n kernel[n,k,l]
//
// Grid: LL * (BB/2) blocks; block = 256 threads = 2 batch-subs x 128 float2 cols.
// float2-per-thread keeps xv[] at 50 VGPR -> ~4 waves/SIMD (vs 2 with float4).
__global__ __launch_bounds__(256, 4) void GCNLayer_72602127172024_kernel(
    const float* __restrict__ x,     // [B,L,J,C]
    const float* __restrict__ A,     // [J,J]
    const float* __restrict__ kern,  // [F,K,L]
    float* __restrict__ out)         // [L,B,J,C]
{
    __shared__ float w_sh[KK];
    __shared__ __align__(16) float Ms[JJ * JPAD];  // Ms[i*JPAD+j] = M[i][j], pad zeroed

    const int tid = threadIdx.x;
    const int gid = blockIdx.x;
    const int l   = gid >> 10;          // / (BB/2) == /1024
    const int bb  = (gid & 1023) << 1;  // base batch of this block (2 consecutive b)

    // ---- w[k] = sum_n kern[n*K*L + k*L + l]; wave k handles hop k, lane = n ----
    {
        const int k    = tid >> 6;   // wave id == hop (KK==4 waves exactly)
        const int lane = tid & 63;   // filter index (FF==64 exactly)
        float v = kern[lane * (KK * LL) + k * LL + l];
        v += __shfl_xor(v, 32, 64);
        v += __shfl_xor(v, 16, 64);
        v += __shfl_xor(v, 8, 64);
        v += __shfl_xor(v, 4, 64);
        v += __shfl_xor(v, 2, 64);
        v += __shfl_xor(v, 1, 64);
        if (lane == 0) w_sh[k] = v;
    }
    __syncthreads();

    const float w0 = w_sh[0], w1 = w_sh[1], w2 = w_sh[2], w3 = w_sh[3];

    // ---- build Ms[i][j] (row-major, padded); pad entries set to 0 ----
    for (int e = tid; e < JJ * JPAD; e += 256) {
        const int i = e / JPAD;
        const int j = e - i * JPAD;
        float m = 0.0f;
        if (j < JJ) {
            const float a = A[i * JJ + j];
            m = w0 + a * (w1 + a * (w2 + a * w3));   // Horner; a=0 -> w0 (0^0==1)
        }
        Ms[e] = m;
    }
    __syncthreads();

    // ---- main: each thread owns one float2 column of one (b,l) slab ----
    const int bsub = tid >> 7;        // 0..1
    const int c2   = tid & 127;       // float2 column (CC/2 == 128)
    const int b    = bb + bsub;

    const f2* __restrict__ xin =
        reinterpret_cast<const f2*>(x) + ((b * LL + l) * JJ) * 128 + c2;
    f2* __restrict__ oout =
        reinterpret_cast<f2*>(out) + ((l * BB + b) * JJ) * 128 + c2;

    // Load the full [J] column slab into registers (25 x float2 = 50 VGPR),
    // coalesced (wave reads 512B per instruction). Nontemporal: pure stream,
    // no reuse -> don't allocate in L2.
    f2 xv[JJ];
#pragma unroll
    for (int j = 0; j < JJ; ++j) xv[j] = __builtin_nontemporal_load(xin + j * 128);

    // For each output joint i: read M row i as 7 float4 LDS broadcasts
    // (uniform address -> conflict-free), accumulate, store immediately.
#pragma unroll
    for (int i = 0; i < JJ; ++i) {
        const f4* mrow = reinterpret_cast<const f4*>(Ms + i * JPAD);
        f2 acc = {0.0f, 0.0f};
#pragma unroll
        for (int j4 = 0; j4 < 7; ++j4) {
            const f4 m4 = mrow[j4];
#pragma unroll
            for (int comp = 0; comp < 4; ++comp) {
                const int j = j4 * 4 + comp;
                if (j < JJ) {   // compile-time pruned (full unroll)
                    const float m = m4[comp];
                    acc.x = fmaf(m, xv[j].x, acc.x);
                    acc.y = fmaf(m, xv[j].y, acc.y);
                }
            }
        }
        __builtin_nontemporal_store(acc, oout + i * 128);
    }
}

extern "C" void kernel_launch(void* const* d_in, const int* in_sizes, int n_in,
                              void* d_out, int out_size, void* d_ws, size_t ws_size,
                              hipStream_t stream) {
    const float* x    = (const float*)d_in[0];   // [B,L,J,C]
    const float* A    = (const float*)d_in[1];   // [J,J]
    const float* kern = (const float*)d_in[2];   // [F,K,L]
    float* out        = (float*)d_out;           // [L,B,J,C]

    const int grid = LL * (BB / 2);  // 20480 blocks
    GCNLayer_72602127172024_kernel<<<grid, 256, 0, stream>>>(x, A, kern, out);
}